// Round 8
// baseline (118.138 us; speedup 1.0000x reference)
//
#include <hip/hip_runtime.h>

// Problem constants
#define D_K   1024      // hidden dim (GEMM K)
#define ROWS  16384     // B*L
#define MLP   500
#define NEG   0.01f

// GEMM geometry: 128x128 tile, 4 waves (64x64 each), BK=32, ring-2 LDS (32KB)
#define BM    128
#define BN    128
#define BK    32
#define NT    (D_K / BK)        // 32 K-tiles
#define ASLOT 8192              // BM*BK*2 bytes
#define BSLOT 8192              // BN*BK*2 bytes

typedef __bf16 bf16x8 __attribute__((ext_vector_type(8)));
typedef __bf16 bf16x4 __attribute__((ext_vector_type(4)));
typedef float  f32x4  __attribute__((ext_vector_type(4)));

#define GL(p) ((const __attribute__((address_space(1))) void*)(p))
#define LD(p) ((__attribute__((address_space(3))) void*)(p))

// f32 -> bf16 RNE via hw cvt
__device__ __forceinline__ ushort bfc(float x) {
    __bf16 b = (__bf16)x;
    return __builtin_bit_cast(ushort, b);
}

// Paired-row LDS swizzle: tiles stored as [row>>1][128B pseudo-rows]
// (row,kbyte) -> (row>>1)*128 + (row&1)*64 + kbyte, then XOR bits 4-6 with
// pseudo-row bits 7-9. Enumerated: 16-row x 16B frag reads land 2 lanes/slot
// (free, m136); staging writes hit 64 distinct 16B slots. Involution.
__device__ __forceinline__ unsigned swz(unsigned x) {
    return x ^ (((x >> 7) & 7u) << 4);
}

// ---------------- prep-lite: W transpose+pad, bias/Wc pad, zero scores ----------------
__global__ __launch_bounds__(256) void prep_lite(const float* __restrict__ Wd,
                                                 const float* __restrict__ bd,
                                                 const float* __restrict__ Wh,
                                                 const float* __restrict__ bh,
                                                 const float* __restrict__ Wc,
                                                 ushort* __restrict__ Bt,
                                                 float* __restrict__ bias_pad,
                                                 float* __restrict__ wc_pad,
                                                 float4* __restrict__ zero_area) {
    __shared__ ushort tbuf[64][72];
    const int bid = blockIdx.x, tid = threadIdx.x;
    if (bid < 256) {
        // W [1024][500] -> Bt bf16 [1024][1024] transposed + zero-padded
        int b = bid;
        const int z = b >> 7; b &= 127;
        const int kx = b & 15, ny = b >> 4;
        const float* W = z ? Wh : Wd;
        const int k0 = kx * 64, n0 = ny * 64;
        const int c = tid & 63, r4 = tid >> 6;
        for (int r = r4; r < 64; r += 4) {
            int n = n0 + c;
            float v = (n < MLP) ? W[(size_t)(k0 + r) * MLP + n] : 0.f;
            tbuf[c][r] = bfc(v);
        }
        __syncthreads();
        const int nbase = z * 512 + n0;
        for (int rr = r4; rr < 64; rr += 4)
            Bt[(size_t)(nbase + rr) * D_K + k0 + c] = tbuf[rr][c];
    } else if (bid < 260) {
        // pad bias + Wc
        int n = (bid - 256) * 256 + tid;   // [0,1024)
        float bv = 0.f, w0 = 0.f, w1 = 0.f;
        if (n < 512) {
            if (n < MLP) { bv = bd[n]; w0 = Wc[n * 2]; w1 = Wc[n * 2 + 1]; }
        } else {
            int m = n - 512;
            if (m < MLP) { bv = bh[m]; w0 = Wc[(MLP + m) * 2]; w1 = Wc[(MLP + m) * 2 + 1]; }
        }
        bias_pad[n] = bv; wc_pad[n * 2] = w0; wc_pad[n * 2 + 1] = w1;
    } else {
        // zero sd+sh (256 KB contiguous)
        int i = (bid - 260) * 256 + tid;   // [0,16384) float4
        zero_area[i] = make_float4(0.f, 0.f, 0.f, 0.f);
    }
}

// ---------------- 128x128 GEMM, 4 blocks/CU, ring-2, 1 barrier/tile ----------------
// A read DIRECTLY from hs (f32): global->reg->cvt->swizzled ds_write.
// B via global_load_lds from pre-transposed bf16 Bt (linear dest, pre-swz source).
// Hazard ledger: see round notes — vmcnt(4) drains BSTAGE(t+1), keeps ALOAD(t+2);
// lgkm0 pre-bar publishes AWRITE + retires own frag reads; WAR separated by bar(t-1).
__global__ __launch_bounds__(256, 4) void gemm_scores(const float* __restrict__ hs,
                                                      const ushort* __restrict__ Bt,
                                                      const float* __restrict__ bias,
                                                      const float* __restrict__ wc,
                                                      float* __restrict__ sd,
                                                      float* __restrict__ sh) {
    __shared__ ushort As[2 * 4096];   // 16 KB
    __shared__ ushort Bs[2 * 4096];   // 16 KB
    const int tid  = threadIdx.x;
    const int lane = tid & 63;
    const int wave = tid >> 6;            // 0..3
    const int wm = wave >> 1, wn = wave & 1;

    // XCD-aware bijective swizzle: 1024 blocks -> 128 consecutive per XCD,
    // so all 8 bn-blocks sharing an A panel land on one XCD's L2.
    const int flat  = blockIdx.x;
    const int sflat = (flat & 7) * 128 + (flat >> 3);
    const int bn = sflat & 7, bm = sflat >> 3;
    const size_t row0 = (size_t)bm * BM;
    const int col0 = bn * BN;

    char* AsB = (char*)As;
    char* BsB = (char*)Bs;

    // B staging (gload_lds): linear LDS dest, inverse-swizzled global source.
    const ushort* bsrc[2];
    unsigned ldst[2];
#pragma unroll
    for (int i = 0; i < 2; ++i) {
        unsigned x = (unsigned)i * 4096u + (unsigned)tid * 16u;
        ldst[i] = x;
        unsigned sx = swz(x);
        unsigned row = (sx >> 7) * 2 + ((sx >> 6) & 1);
        unsigned kb  = sx & 63;
        bsrc[i] = Bt + (size_t)((unsigned)col0 + row) * D_K + (kb >> 1);
    }

    // A reg-staging: thread covers row r = tid>>1, 64B-f32 half h = tid&1.
    const int ar = tid >> 1, ah = tid & 1;
    const f32x4* hsp = (const f32x4*)hs;
    const unsigned aof = (unsigned)((row0 + ar) * 256 + ah * 4);
    unsigned awx[2];
#pragma unroll
    for (int j = 0; j < 2; ++j)
        awx[j] = swz((unsigned)(ar >> 1) * 128u + (unsigned)(ar & 1) * 64u +
                     (unsigned)ah * 32u + (unsigned)j * 16u);

    // frag read offsets (swizzled)
    const unsigned l15 = lane & 15, c16 = (unsigned)(lane >> 4) * 16u;
    unsigned yA[4], yB[4];
#pragma unroll
    for (int m = 0; m < 4; ++m) {
        unsigned R = (unsigned)(wm * 64 + m * 16) + l15;
        yA[m] = swz((R >> 1) * 128u + (R & 1) * 64u + c16);
    }
#pragma unroll
    for (int n = 0; n < 4; ++n) {
        unsigned C = (unsigned)(wn * 64 + n * 16) + l15;
        yB[n] = swz((C >> 1) * 128u + (C & 1) * 64u + c16);
    }

    f32x4 acc[4][4] = {};
    f32x4 R[4];

#define BSTAGE(t) { char* d_ = BsB + ((t) & 1) * BSLOT;                                   \
    __builtin_amdgcn_global_load_lds(GL(bsrc[0] + (t) * BK), LD(d_ + ldst[0]), 16, 0, 0); \
    __builtin_amdgcn_global_load_lds(GL(bsrc[1] + (t) * BK), LD(d_ + ldst[1]), 16, 0, 0); }
#define ALOAD(t) { _Pragma("unroll")                                                      \
    for (int j = 0; j < 4; ++j) R[j] = hsp[aof + (t) * 8 + j]; }
#define AWRITE(t) { char* d_ = AsB + ((t) & 1) * ASLOT; _Pragma("unroll")                 \
    for (int j = 0; j < 2; ++j) {                                                         \
        bf16x4 a_ = __builtin_convertvector(R[2 * j],     bf16x4);                        \
        bf16x4 b_ = __builtin_convertvector(R[2 * j + 1], bf16x4);                        \
        bf16x8 w_ = __builtin_shufflevector(a_, b_, 0, 1, 2, 3, 4, 5, 6, 7);              \
        *(bf16x8*)(d_ + awx[j]) = w_; } }

    // Prologue: tile 0 fully staged; R holds tile 1.
    BSTAGE(0);
    ALOAD(0);
    AWRITE(0);          // implicit vmcnt wait on R drains BSTAGE(0) too
    ALOAD(1);
    asm volatile("s_waitcnt lgkmcnt(0)" ::: "memory");
    __builtin_amdgcn_s_barrier();

    for (int t = 0; t < NT; ++t) {
        const int sl = t & 1;
        char* Asl = AsB + sl * ASLOT;
        char* Bsl = BsB + sl * BSLOT;

        bf16x8 af[4], bf[4];
#pragma unroll
        for (int m = 0; m < 4; ++m) af[m] = *(const bf16x8*)(Asl + yA[m]);
#pragma unroll
        for (int n = 0; n < 4; ++n) bf[n] = *(const bf16x8*)(Bsl + yB[n]);

        if (t + 1 < NT) {
            BSTAGE(t + 1);
            AWRITE(t + 1);           // consumes R (tile t+1, loaded at t-1)
        }
        if (t + 2 < NT) {
            ALOAD(t + 2);            // refill R
            asm volatile("s_waitcnt vmcnt(4)" ::: "memory");  // drain BSTAGE(t+1), keep ALOAD
        } else {
            asm volatile("s_waitcnt vmcnt(0)" ::: "memory");
        }
        asm volatile("s_waitcnt lgkmcnt(0)" ::: "memory");    // frag reads + AWRITE published
        __builtin_amdgcn_s_barrier();
        __builtin_amdgcn_sched_barrier(0);
        __builtin_amdgcn_s_setprio(1);
#pragma unroll
        for (int m = 0; m < 4; ++m)
#pragma unroll
            for (int n = 0; n < 4; ++n)
                acc[m][n] = __builtin_amdgcn_mfma_f32_16x16x32_bf16(af[m], bf[n], acc[m][n], 0, 0, 0);
        __builtin_amdgcn_s_setprio(0);
        __builtin_amdgcn_sched_barrier(0);
    }
#undef BSTAGE
#undef ALOAD
#undef AWRITE

    // Epilogue: bias + leakyrelu + rank-2 contraction, 16-lane reduce, atomic add.
    // C/D layout: col = lane&15, row = (lane>>4)*4 + reg  [m89-verified]
    float bv[4], w0v[4], w1v[4];
#pragma unroll
    for (int nf = 0; nf < 4; ++nf) {
        int cc = col0 + wn * 64 + nf * 16 + (int)l15;
        bv[nf] = bias[cc]; w0v[nf] = wc[2 * cc]; w1v[nf] = wc[2 * cc + 1];
    }
    float* S = (bn < 4) ? sd : sh;
#pragma unroll
    for (int mf = 0; mf < 4; ++mf) {
        size_t rowb = row0 + (size_t)(wm * 64 + mf * 16 + (lane >> 4) * 4);
#pragma unroll
        for (int r = 0; r < 4; ++r) {
            float s0 = 0.f, s1 = 0.f;
#pragma unroll
            for (int nf = 0; nf < 4; ++nf) {
                float h = acc[mf][nf][r] + bv[nf];
                h = (h > 0.f) ? h : NEG * h;
                s0 += h * w0v[nf]; s1 += h * w1v[nf];
            }
#pragma unroll
            for (int m = 1; m < 16; m <<= 1) {
                s0 += __shfl_xor(s0, m, 64);
                s1 += __shfl_xor(s1, m, 64);
            }
            if (l15 == 0) {
                atomicAdd(&S[(rowb + r) * 2 + 0], s0);
                atomicAdd(&S[(rowb + r) * 2 + 1], s1);
            }
        }
    }
}

// ---------------- broadcast add: out[b,i,j,c] = sd[b,i,c] + sh[b,j,c] + bc[c] ----------------
__global__ __launch_bounds__(256) void bcast(const float* __restrict__ sd,
                                             const float* __restrict__ sh,
                                             const float* __restrict__ bc,
                                             float* __restrict__ out) {
    const int bi = blockIdx.x;            // b*1024 + i
    const int b  = bi >> 10;
    const float v0 = sd[bi * 2 + 0] + bc[0];
    const float v1 = sd[bi * 2 + 1] + bc[1];
    const f32x4* shrow = (const f32x4*)(sh + (size_t)b * 2048);
    f32x4* orow = (f32x4*)(out + (size_t)bi * 2048);
#pragma unroll
    for (int t = threadIdx.x; t < 512; t += 256) {
        f32x4 s = shrow[t];
        f32x4 o;
        o.x = v0 + s.x; o.y = v1 + s.y; o.z = v0 + s.z; o.w = v1 + s.w;
        __builtin_nontemporal_store(o, &orow[t]);
    }
}

extern "C" void kernel_launch(void* const* d_in, const int* in_sizes, int n_in,
                              void* d_out, int out_size, void* d_ws, size_t ws_size,
                              hipStream_t stream) {
    const float* hs = (const float*)d_in[0];
    const float* Wd = (const float*)d_in[1];
    const float* bd = (const float*)d_in[2];
    const float* Wh = (const float*)d_in[3];
    const float* bh = (const float*)d_in[4];
    const float* Wc = (const float*)d_in[5];
    const float* bc = (const float*)d_in[6];
    float* out = (float*)d_out;

    char* ws = (char*)d_ws;
    ushort* Bt   = (ushort*)(ws);                 // 2,097,152 B
    float*  bias = (float*) (ws + 2097152);       // 4 KB
    float*  wcp  = (float*) (ws + 2101248);       // 8 KB
    float*  sd   = (float*) (ws + 2109440);       // 128 KB
    float*  sh   = (float*) (ws + 2240512);       // 128 KB (contiguous after sd)

    prep_lite<<<324, 256, 0, stream>>>(Wd, bd, Wh, bh, Wc, Bt, bias, wcp, (float4*)sd);
    gemm_scores<<<1024, 256, 0, stream>>>(hs, Bt, bias, wcp, sd, sh);
    bcast<<<ROWS, 256, 0, stream>>>(sd, sh, bc, out);
}